// Round 8
// baseline (141.494 us; speedup 1.0000x reference)
//
#include <hip/hip_runtime.h>

typedef unsigned short u16;
typedef unsigned int u32;
typedef short bf8 __attribute__((ext_vector_type(8)));   // 8 bf16 = 4 VGPR (MFMA A/B frag)
typedef float f4v __attribute__((ext_vector_type(4)));   // 16x16 C/D frag
typedef float f16v __attribute__((ext_vector_type(16))); // 32x32 C/D frag

__device__ __forceinline__ u32 f2bf(float f){
    union{float f;u32 i;}c; c.f=f; u32 i=c.i;
    return (i + 0x7FFFu + ((i>>16)&1u)) >> 16;  // RNE
}

// XOR-swizzled LDS addressing: 64x64 bf16, stride 64 (8192 B), chunk = 8 cols.
// addr(row, chunk) in u16 units; 16B-aligned per chunk.
__device__ __forceinline__ int sw(int row, int chunk){
    return row*64 + ((chunk ^ (row & 7)) << 3);
}

// ================= precompute kernel: batch-invariant prep + per-(b,h) pos softmax =================
__global__ __launch_bounds__(256) void pre_kernel(
    const float* __restrict__ pos, const float* __restrict__ strength,
    const int* __restrict__ embed_id,
    const float* __restrict__ Wq, const float* __restrict__ Wk,
    const float* __restrict__ pW1, const float* __restrict__ pb1,
    const float* __restrict__ pW2, const float* __restrict__ pb2,
    const float* __restrict__ hW, const float* __restrict__ embeds,
    const float* __restrict__ oW, const float* __restrict__ sW,
    const float* __restrict__ sb,
    float* __restrict__ ws_s64, float* __restrict__ ws_pat,
    u16* __restrict__ ws_wq, u16* __restrict__ ws_wk,
    u16* __restrict__ ws_ow, u16* __restrict__ ws_e, int B)
{
    const int blk = blockIdx.x;
    const int t = threadIdx.x;

    if (blk < B) {
        __shared__ float t_l[4][64];
        if (t < 64) {
            float pv[4], h1[4], p8[8];
            const float* gp = pos + ((size_t)blk*64 + t)*4;
            #pragma unroll
            for (int i = 0; i < 4; ++i) pv[i] = gp[i];
            #pragma unroll
            for (int j = 0; j < 4; ++j){
                float a = pb1[j];
                #pragma unroll
                for (int i = 0; i < 4; ++i) a = fmaf(pv[i], pW1[i*4+j], a);
                h1[j] = fmaxf(a, 0.f);
            }
            #pragma unroll
            for (int f = 0; f < 8; ++f){
                float a = pb2[f];
                #pragma unroll
                for (int j = 0; j < 4; ++j) a = fmaf(h1[j], pW2[j*8+f], a);
                p8[f] = a;
            }
            #pragma unroll
            for (int h = 0; h < 4; ++h){
                float a = 0.f;
                #pragma unroll
                for (int f = 0; f < 8; ++f) a = fmaf(p8[f], hW[f*4+h], a);
                t_l[h][t] = a;
            }
        }
        __syncthreads();
        const int h = t >> 6, k = t & 63;
        float v0 = -t_l[h][k];
        float m = v0;
        #pragma unroll
        for (int off = 32; off; off >>= 1) m = fmaxf(m, __shfl_xor(m, off));
        float e = __expf(v0 - m);
        float ssum = e;
        #pragma unroll
        for (int off = 32; off; off >>= 1) ssum += __shfl_xor(ssum, off);
        ws_pat[((size_t)blk*4 + h)*64 + k] = e / ssum;
        return;
    }

    const int j = blk - B;
    if (j < 3) {
        // transpose W[64 in][64 out] fp32 -> bf16 [out][in], stride 64
        const float* W = (j==0) ? Wq : (j==1) ? Wk : oW;
        u16* dst = (j==0) ? ws_wq : (j==1) ? ws_wk : ws_ow;
        const int kp = t >> 3, ng = t & 7;
        const float4* r0 = (const float4*)(W + (2*kp  )*64 + 8*ng);
        const float4* r1 = (const float4*)(W + (2*kp+1)*64 + 8*ng);
        float4 a0=r0[0], a1=r0[1], b0=r1[0], b1=r1[1];
        float lo[8]={a0.x,a0.y,a0.z,a0.w,a1.x,a1.y,a1.z,a1.w};
        float hi[8]={b0.x,b0.y,b0.z,b0.w,b1.x,b1.y,b1.z,b1.w};
        #pragma unroll
        for (int i=0;i<8;++i)
            *(u32*)&dst[(8*ng+i)*64 + 2*kp] = f2bf(lo[i]) | (f2bf(hi[i])<<16);
    } else {
        // E = embeds[id] -> bf16 row-major; s64 = strength @ str_W + str_b
        __shared__ float sp[4][64];
        {
            const int n = t >> 2, c0 = (t & 3) << 4;
            const float4* p = (const float4*)(embeds + (size_t)(*embed_id)*4096 + n*64 + c0);
            float4 a=p[0], b=p[1], c=p[2], d=p[3];
            uint4 o0, o1;
            o0.x = f2bf(a.x)|(f2bf(a.y)<<16); o0.y = f2bf(a.z)|(f2bf(a.w)<<16);
            o0.z = f2bf(b.x)|(f2bf(b.y)<<16); o0.w = f2bf(b.z)|(f2bf(b.w)<<16);
            o1.x = f2bf(c.x)|(f2bf(c.y)<<16); o1.y = f2bf(c.z)|(f2bf(c.w)<<16);
            o1.z = f2bf(d.x)|(f2bf(d.y)<<16); o1.w = f2bf(d.z)|(f2bf(d.w)<<16);
            *(uint4*)&ws_e[n*64 + c0]     = o0;
            *(uint4*)&ws_e[n*64 + c0 + 8] = o1;
        }
        {
            const int d = t & 63, part = t >> 6;
            const float* wp = sW + part*128*64 + d;
            const float* s  = strength + part*128;
            float acc = 0.f;
            #pragma unroll 8
            for (int i = 0; i < 128; ++i) acc = fmaf(s[i], wp[i*64], acc);
            sp[part][d] = acc;
        }
        __syncthreads();
        if (t < 64) ws_s64[t] = sp[0][t] + sp[1][t] + sp[2][t] + sp[3][t] + sb[t];
    }
}

// ================= main kernel =================
__global__ __launch_bounds__(256, 2) void attn_main_kernel(
    const float* __restrict__ x, const float* __restrict__ gate, const float* __restrict__ ob,
    const float* __restrict__ ws_s64, const float* __restrict__ ws_pat,
    const u16* __restrict__ ws_wq, const u16* __restrict__ ws_wk,
    const u16* __restrict__ ws_ow, const u16* __restrict__ ws_e,
    float* __restrict__ out)
{
    // 5 x 8192 B = 40960 B -> 3-4 blocks/CU
    __shared__ short W1[4096];   // WqT -> E -> P(h0) -> oWT
    __shared__ short W2[4096];   // WkT -> V^T
    __shared__ short QB[4096];   // Q -> P(h2) -> ctx
    __shared__ short KB[4096];   // K -> P(h3)
    __shared__ short PB[4096];   // P(h1)

    const int t    = threadIdx.x;
    const int b    = blockIdx.x;
    const int lane = t & 63;
    const int w    = t >> 6;        // wave id = head id
    const int l15  = lane & 15;
    const int l31  = lane & 31;
    const int l5   = lane >> 5;
    const int quad = lane >> 4;

    // ---- P0: stage WqT->W1, WkT->W2 (swizzled); x/E/oW/s64/pattn/gate -> regs ----
    {
        const int r = t >> 2, cp = (t & 3) * 2;   // row, chunk-pair
        const uint4* sq = (const uint4*)(ws_wq + r*64 + cp*8);
        uint4 qa = sq[0], qb = sq[1];
        *(uint4*)&W1[sw(r, cp)]   = qa;
        *(uint4*)&W1[sw(r, cp+1)] = qb;
        const uint4* sk = (const uint4*)(ws_wk + r*64 + cp*8);
        uint4 ka = sk[0], kb = sk[1];
        *(uint4*)&W2[sw(r, cp)]   = ka;
        *(uint4*)&W2[sw(r, cp+1)] = kb;
    }
    // x A-frags: wave w rows 16w+l15, k-chunks quad and quad+4 (8 fp32 each)
    bf8 xa0, xa1;
    {
        const float* xp = x + (size_t)b*4096 + (16*w + l15)*64 + quad*8;
        float4 f0 = *(const float4*)xp,      f1 = *(const float4*)(xp+4);
        float4 f2 = *(const float4*)(xp+32), f3 = *(const float4*)(xp+36);
        union { short s[8]; bf8 v; } A0, A1;
        A0.s[0]=(short)f2bf(f0.x); A0.s[1]=(short)f2bf(f0.y); A0.s[2]=(short)f2bf(f0.z); A0.s[3]=(short)f2bf(f0.w);
        A0.s[4]=(short)f2bf(f1.x); A0.s[5]=(short)f2bf(f1.y); A0.s[6]=(short)f2bf(f1.z); A0.s[7]=(short)f2bf(f1.w);
        A1.s[0]=(short)f2bf(f2.x); A1.s[1]=(short)f2bf(f2.y); A1.s[2]=(short)f2bf(f2.z); A1.s[3]=(short)f2bf(f2.w);
        A1.s[4]=(short)f2bf(f3.x); A1.s[5]=(short)f2bf(f3.y); A1.s[6]=(short)f2bf(f3.z); A1.s[7]=(short)f2bf(f3.w);
        xa0 = A0.v; xa1 = A1.v;
    }
    uint4 eA, eB, owA, owB;
    {
        const int r = t >> 2, cs = (t & 3) << 4;
        const uint4* se = (const uint4*)(ws_e + r*64 + cs);
        eA = se[0]; eB = se[1];
        const uint4* so = (const uint4*)(ws_ow + r*64 + cs);
        owA = so[0]; owB = so[1];
    }
    float svv[4];
    #pragma unroll
    for (int nt=0;nt<4;++nt) svv[nt] = ws_s64[16*nt + l15];
    float g = 1.f/(1.f + __expf(-gate[w]));
    float obv[4];
    #pragma unroll
    for (int nt=0;nt<4;++nt) obv[nt] = ob[16*nt + l15];
    float ep[32];
    {
        const float* pp = ws_pat + ((size_t)b*4 + w)*64;
        #pragma unroll
        for (int mt=0;mt<2;++mt)
            #pragma unroll
            for (int rg=0;rg<4;++rg){
                float4 tv = *(const float4*)&pp[32*mt + 8*rg + 4*l5];
                ep[mt*16+rg*4+0] = g*tv.x; ep[mt*16+rg*4+1] = g*tv.y;
                ep[mt*16+rg*4+2] = g*tv.z; ep[mt*16+rg*4+3] = g*tv.w;
            }
    }
    __syncthreads();   // sync1

    // ---- P1: q = x@Wq, k = x@Wk (A from regs) ----
    f4v cq[4], ck[4];
    #pragma unroll
    for (int nt=0;nt<4;++nt){
        cq[nt][0]=0.f;cq[nt][1]=0.f;cq[nt][2]=0.f;cq[nt][3]=0.f;
        ck[nt][0]=0.f;ck[nt][1]=0.f;ck[nt][2]=0.f;ck[nt][3]=0.f;
        bf8 b0 = *(const bf8*)&W1[sw(16*nt+l15, quad)];
        bf8 b1 = *(const bf8*)&W1[sw(16*nt+l15, quad+4)];
        cq[nt] = __builtin_amdgcn_mfma_f32_16x16x32_bf16(xa0, b0, cq[nt], 0,0,0);
        cq[nt] = __builtin_amdgcn_mfma_f32_16x16x32_bf16(xa1, b1, cq[nt], 0,0,0);
        bf8 d0 = *(const bf8*)&W2[sw(16*nt+l15, quad)];
        bf8 d1 = *(const bf8*)&W2[sw(16*nt+l15, quad+4)];
        ck[nt] = __builtin_amdgcn_mfma_f32_16x16x32_bf16(xa0, d0, ck[nt], 0,0,0);
        ck[nt] = __builtin_amdgcn_mfma_f32_16x16x32_bf16(xa1, d1, ck[nt], 0,0,0);
    }
    __syncthreads();   // sync2: W1/W2 frag reads done

    // q -> QB (*0.25), k -> KB, E(regs) -> W1
    #pragma unroll
    for (int nt=0;nt<4;++nt){
        const int ch = 2*nt + (l15>>3), off = l15 & 7;
        #pragma unroll
        for (int r=0;r<4;++r){
            const int row = 16*w + quad*4 + r;
            QB[sw(row, ch) + off] = (short)f2bf(0.25f*cq[nt][r]);
            KB[sw(row, ch) + off] = (short)f2bf(ck[nt][r]);
        }
    }
    {
        const int r = t >> 2, cp = (t & 3) * 2;
        *(uint4*)&W1[sw(r, cp)]   = eA;
        *(uint4*)&W1[sw(r, cp+1)] = eB;
    }
    __syncthreads();   // sync3: Q, K, E visible

    // ---- P2: v = x@E^T -> V^T into W2 ----
    {
        f4v cv[4];
        #pragma unroll
        for (int nt=0;nt<4;++nt){
            cv[nt][0]=0.f;cv[nt][1]=0.f;cv[nt][2]=0.f;cv[nt][3]=0.f;
            bf8 b0 = *(const bf8*)&W1[sw(16*nt+l15, quad)];
            bf8 b1 = *(const bf8*)&W1[sw(16*nt+l15, quad+4)];
            cv[nt] = __builtin_amdgcn_mfma_f32_16x16x32_bf16(xa0, b0, cv[nt], 0,0,0);
            cv[nt] = __builtin_amdgcn_mfma_f32_16x16x32_bf16(xa1, b1, cv[nt], 0,0,0);
        }
        const int ch = 2*w + (quad>>1), off = (quad&1)*4;
        #pragma unroll
        for (int nt=0;nt<4;++nt){
            float sv = svv[nt];
            uint2 pk;
            pk.x = f2bf(cv[nt][0]+sv) | (f2bf(cv[nt][1]+sv)<<16);
            pk.y = f2bf(cv[nt][2]+sv) | (f2bf(cv[nt][3]+sv)<<16);
            *(uint2*)&W2[sw(16*nt+l15, ch) + off] = pk;   // V^T[dim][key]
        }
    }

    // ---- P4: S^T = K@Q^T (32x32x16); softmax + gate-mix in C/D layout ----
    f16v S[2][2];
    {
        bf8 ka0 = *(const bf8*)&KB[sw(     l31, 2*w + l5)];
        bf8 ka1 = *(const bf8*)&KB[sw(32 + l31, 2*w + l5)];
        bf8 qb0 = *(const bf8*)&QB[sw(     l31, 2*w + l5)];
        bf8 qb1 = *(const bf8*)&QB[sw(32 + l31, 2*w + l5)];
        #pragma unroll
        for (int mt=0;mt<2;++mt)
            #pragma unroll
            for (int nt=0;nt<2;++nt)
                #pragma unroll
                for (int i=0;i<16;++i) S[mt][nt][i] = 0.f;
        S[0][0] = __builtin_amdgcn_mfma_f32_32x32x16_bf16(ka0, qb0, S[0][0], 0,0,0);
        S[0][1] = __builtin_amdgcn_mfma_f32_32x32x16_bf16(ka0, qb1, S[0][1], 0,0,0);
        S[1][0] = __builtin_amdgcn_mfma_f32_32x32x16_bf16(ka1, qb0, S[1][0], 0,0,0);
        S[1][1] = __builtin_amdgcn_mfma_f32_32x32x16_bf16(ka1, qb1, S[1][1], 0,0,0);
    }
    float inv[2];
    #pragma unroll
    for (int nt=0;nt<2;++nt){   // two q columns per lane
        float m = S[0][nt][0];
        #pragma unroll
        for (int i=1;i<16;++i) m = fmaxf(m, S[0][nt][i]);
        #pragma unroll
        for (int i=0;i<16;++i) m = fmaxf(m, S[1][nt][i]);
        m = fmaxf(m, __shfl_xor(m, 32));
        float l = 0.f;
        #pragma unroll
        for (int mt=0;mt<2;++mt)
            #pragma unroll
            for (int i=0;i<16;++i){ float e = __expf(S[mt][nt][i]-m); S[mt][nt][i] = e; l += e; }
        l += __shfl_xor(l, 32);
        float c1 = (1.f - g) / l;
        float tot = 0.f;
        #pragma unroll
        for (int mt=0;mt<2;++mt)
            #pragma unroll
            for (int i=0;i<16;++i){ float a = fmaf(c1, S[mt][nt][i], ep[mt*16+i]); S[mt][nt][i] = a; tot += a; }
        tot += __shfl_xor(tot, 32);
        inv[nt] = 1.f / tot;
    }
    __syncthreads();   // sync4: V^T visible; Q/K/W1 frag reads done

    // ---- P5: P writeback row-major (swizzled, b64 packs) to per-head buffer ----
    short* Pb = (w==0) ? W1 : (w==1) ? PB : (w==2) ? QB : KB;
    #pragma unroll
    for (int nt=0;nt<2;++nt)
        #pragma unroll
        for (int mt=0;mt<2;++mt)
            #pragma unroll
            for (int rg=0;rg<4;++rg){
                float v0 = S[mt][nt][rg*4+0]*inv[nt], v1 = S[mt][nt][rg*4+1]*inv[nt];
                float v2 = S[mt][nt][rg*4+2]*inv[nt], v3 = S[mt][nt][rg*4+3]*inv[nt];
                uint2 pk;
                pk.x = f2bf(v0) | (f2bf(v1)<<16);
                pk.y = f2bf(v2) | (f2bf(v3)<<16);
                *(uint2*)&Pb[sw(32*nt + l31, 4*mt + rg) + 4*l5] = pk;
            }
    // no barrier: P6 reads only this wave's own Pb (same-wave LDS ordering)

    // ---- P6: O_h = P_h @ V_h (16x16x32) ----
    f4v o[4];
    {
        bf8 bv0 = *(const bf8*)&W2[sw(16*w+l15, quad)];
        bf8 bv1 = *(const bf8*)&W2[sw(16*w+l15, quad+4)];
        #pragma unroll
        for (int mt=0;mt<4;++mt){
            o[mt][0]=0.f;o[mt][1]=0.f;o[mt][2]=0.f;o[mt][3]=0.f;
            bf8 a0 = *(const bf8*)&Pb[sw(16*mt+l15, quad)];
            bf8 a1 = *(const bf8*)&Pb[sw(16*mt+l15, quad+4)];
            o[mt] = __builtin_amdgcn_mfma_f32_16x16x32_bf16(a0, bv0, o[mt], 0,0,0);
            o[mt] = __builtin_amdgcn_mfma_f32_16x16x32_bf16(a1, bv1, o[mt], 0,0,0);
        }
    }
    __syncthreads();   // sync5: all P reads done

    // ---- P7: ctx -> QB; oWT(regs) -> W1 ----
    {
        const int ch = 2*w + (l15>>3), off = l15 & 7;
        #pragma unroll
        for (int mt=0;mt<4;++mt)
            #pragma unroll
            for (int r=0;r<4;++r)
                QB[sw(16*mt + quad*4 + r, ch) + off] = (short)f2bf(o[mt][r]);
        const int rr = t >> 2, cp = (t & 3) * 2;
        *(uint4*)&W1[sw(rr, cp)]   = owA;
        *(uint4*)&W1[sw(rr, cp+1)] = owB;
    }
    __syncthreads();   // sync6

    // ---- P8: out = ctx@oW + ob -> global ----
    {
        bf8 a0 = *(const bf8*)&QB[sw(16*w+l15, quad)];
        bf8 a1 = *(const bf8*)&QB[sw(16*w+l15, quad+4)];
        #pragma unroll
        for (int nt=0;nt<4;++nt){
            f4v c;
            c[0]=obv[nt];c[1]=obv[nt];c[2]=obv[nt];c[3]=obv[nt];
            bf8 b0 = *(const bf8*)&W1[sw(16*nt+l15, quad)];
            bf8 b1 = *(const bf8*)&W1[sw(16*nt+l15, quad+4)];
            c = __builtin_amdgcn_mfma_f32_16x16x32_bf16(a0, b0, c, 0,0,0);
            c = __builtin_amdgcn_mfma_f32_16x16x32_bf16(a1, b1, c, 0,0,0);
            #pragma unroll
            for (int r=0;r<4;++r)
                out[((size_t)b*64 + 16*w + quad*4 + r)*64 + 16*nt + l15] = c[r];
        }
    }
}

extern "C" void kernel_launch(void* const* d_in, const int* in_sizes, int n_in,
                              void* d_out, int out_size, void* d_ws, size_t ws_size,
                              hipStream_t stream) {
    const int B = in_sizes[0] / (64 * 64);  // 2048

    // workspace carve (2.03 MB): s64 | pattn | WqT | WkT | oWT | E (bf16)
    float* ws_s64 = (float*)d_ws;
    float* ws_pat = ws_s64 + 64;
    u16*   ws_wq  = (u16*)(ws_pat + (size_t)B*4*64);
    u16*   ws_wk  = ws_wq + 4096;
    u16*   ws_ow  = ws_wk + 4096;
    u16*   ws_e   = ws_ow + 4096;

    pre_kernel<<<B + 4, 256, 0, stream>>>(
        (const float*)d_in[1],  (const float*)d_in[2],  (const int*)d_in[3],
        (const float*)d_in[4],  (const float*)d_in[5],
        (const float*)d_in[6],  (const float*)d_in[7],  (const float*)d_in[8],  (const float*)d_in[9],
        (const float*)d_in[10], (const float*)d_in[13], (const float*)d_in[14],
        (const float*)d_in[16], (const float*)d_in[17],
        ws_s64, ws_pat, ws_wq, ws_wk, ws_ow, ws_e, B);

    attn_main_kernel<<<B, 256, 0, stream>>>(
        (const float*)d_in[0],  (const float*)d_in[12], (const float*)d_in[15],
        ws_s64, ws_pat, ws_wq, ws_wk, ws_ow, ws_e,
        (float*)d_out);
}